// Round 11
// baseline (339.418 us; speedup 1.0000x reference)
//
#include <hip/hip_runtime.h>

// LinearCrossAttention: B=16, N=4096, M=1024, C_in=C_cond=512, HIDDEN=512
#define KDIM 512

typedef __attribute__((ext_vector_type(8))) short bf16x8;
typedef __attribute__((ext_vector_type(4))) float f32x4;
typedef unsigned short u16;
typedef unsigned int u32;

static __device__ __forceinline__ u16 f2bf(float f) {
  u32 u = __builtin_bit_cast(u32, f);
  u32 r = u + 0x7fffu + ((u >> 16) & 1u);   // round-to-nearest-even
  return (u16)(r >> 16);
}
static __device__ __forceinline__ bf16x8 ld_frag(const u16* p) {
  uint2 lo = *(const uint2*)p;
  uint2 hi = *(const uint2*)(p + 4);
  uint4 u = make_uint4(lo.x, lo.y, hi.x, hi.y);
  return __builtin_bit_cast(bf16x8, u);
}

// ---------------------------------------------------------------------------
// prep: f32 -> bf16 (for Wkv), 8 elems/thread
// ---------------------------------------------------------------------------
__global__ __launch_bounds__(256) void cvt_f32_bf16(
    const float* __restrict__ src, u16* __restrict__ dst, int n8)
{
  int i = blockIdx.x * 256 + threadIdx.x;
  if (i >= n8) return;
  float4 a = *(const float4*)(src + (long)i * 8);
  float4 b = *(const float4*)(src + (long)i * 8 + 4);
  u32 w0 = (u32)f2bf(a.x) | ((u32)f2bf(a.y) << 16);
  u32 w1 = (u32)f2bf(a.z) | ((u32)f2bf(a.w) << 16);
  u32 w2 = (u32)f2bf(b.x) | ((u32)f2bf(b.y) << 16);
  u32 w3 = (u32)f2bf(b.z) | ((u32)f2bf(b.w) << 16);
  *(uint4*)(dst + (long)i * 8) = make_uint4(w0, w1, w2, w3);
}

// ---------------------------------------------------------------------------
// gemm_s: BM=512 / BN=64 / BK=32, 512 thr = 8 waves (8M x 1N), per-wave
// 64x64 out (acc = 64 AGPR).  2 blocks/CU: LDS 74 KB, <=128 unified regs
// (__launch_bounds__(512,4)).
// KEY CHANGE vs R8: raw s_barrier + lgkmcnt(0)-only fence instead of
// __syncthreads.  hipcc drains vmcnt(0) before every __syncthreads (the m97
// barrier-drain), killing the prefetch pipeline each K-step.  With the raw
// barrier, STAGE's vmcnt wait is dependency-counted (only the loads it
// consumes are drained; this step's prefetch loads stay in flight) — T3/T4.
// Race ledger: each wave's frag ds_reads of buf X complete before its
// lgkmcnt(0) fence -> after barrier, X may be overwritten; trailing ""
// memory-clobber stops next-step ds_reads hoisting above the barrier.
// A (L2-resident panel): reg-staged, depth-1 prefetch, ZERO-pad rows (64B)
// with granule XOR swizzle  pos = g ^ ((row>>2)&3)  -> all b128, 2-way max
// (free, m136).  B (streaming, HBM): reg-staged depth-2, rows padded to
// 20 u32 (80B, b128-aligned), k-pair XOR placement (R9-verified).
// ---------------------------------------------------------------------------
#define A0OFF 0
#define A1OFF 16384
#define B0OFF 32768
#define B1OFF 35328

#define S_LOADB(set, kt) { \
  pb##set##a = *(const float2*)(Bb + (long)((kt) + 2 * kp)     * ldn + n2); \
  pb##set##b = *(const float2*)(Bb + (long)((kt) + 2 * kp + 1) * ldn + n2); }

#define S_LOADA(kt) { _Pragma("unroll") \
  for (int i_ = 0; i_ < 4; ++i_) \
    pa[i_] = *(const uint4*)(Ab + (long)(arow + i_ * 128) * KDIM + (kt) + ac * 8); }

#define S_STAGE(bset, ab, bb) { \
  _Pragma("unroll") for (int i_ = 0; i_ < 4; ++i_) \
    *(uint4*)&lds[(ab) + (arow + i_ * 128) * 32 + awsel] = pa[i_]; \
  u32 w0_ = (u32)f2bf(pb##bset##a.x) | ((u32)f2bf(pb##bset##b.x) << 16); \
  u32 w1_ = (u32)f2bf(pb##bset##a.y) | ((u32)f2bf(pb##bset##b.y) << 16); \
  u32* B32_ = (u32*)&lds[bb]; \
  B32_[bw0] = w0_; B32_[bw1] = w1_; }

#define S_MFMA(ab, bb) { \
  bf16x8 bfr_[4]; \
  _Pragma("unroll") for (int ni_ = 0; ni_ < 4; ++ni_) \
    bfr_[ni_] = *(const bf16x8*)&lds[(bb) + (ni_ * 16 + lrow) * 40 + brsel]; \
  __builtin_amdgcn_s_setprio(1); \
  _Pragma("unroll") for (int mi_ = 0; mi_ < 4; ++mi_) { \
    bf16x8 af_ = *(const bf16x8*)&lds[(ab) + (wv * 64 + mi_ * 16 + lrow) * 32 + arsel]; \
    _Pragma("unroll") for (int ni_ = 0; ni_ < 4; ++ni_) \
      acc[mi_][ni_] = __builtin_amdgcn_mfma_f32_16x16x32_bf16(af_, bfr_[ni_], acc[mi_][ni_], 0, 0, 0); } \
  __builtin_amdgcn_s_setprio(0); }

#define S_SYNC() { \
  asm volatile("s_waitcnt lgkmcnt(0)" ::: "memory"); \
  __builtin_amdgcn_s_barrier(); \
  asm volatile("" ::: "memory"); }

template<bool OUT_BF16, bool BIAS, int MT, int NT>
__global__ __launch_bounds__(512, 4) void gemm_s(
    const u16* __restrict__ Ap, long a_bstride,
    const float* __restrict__ Bp, long b_bstride,
    void* __restrict__ Op, long o_bstride,
    const float* __restrict__ bias, int ldn)
{
  __shared__ u16 lds[37888];               // 75.8 KB: A 2x32KB (swizzled), B 2x5KB

  const int d = blockIdx.x;                // mt innermost
  const int mt = d % MT;
  const int nt = (d / MT) % NT;
  const int b  = d / (MT * NT);
  const long mtile = (long)mt * 512;
  const long ntile = (long)nt * 64;
  const u16* Ab = Ap + (long)b * a_bstride + mtile * KDIM;
  const float* Bb = Bp + (long)b * b_bstride + ntile;

  const int t = threadIdx.x;
  const int lane = t & 63, wv = t >> 6;
  const int lrow = lane & 15, lkh = lane >> 4;

  // A staging map: 4 threads/row, rows arow+128i, 16B granule ac
  const int arow = t >> 2, ac = t & 3;
  const int awsel = (ac ^ ((arow >> 2) & 3)) * 8;          // swizzled granule (u16)
  // A frag read swizzle (row>>2)&3 == (lrow>>2)&3
  const int arsel = (lkh ^ ((lrow >> 2) & 3)) * 8;
  // B staging map: k-pair kp, col pair (n2, n2+1)
  const int n2 = (t & 31) * 2;
  const int kp = t >> 5;                                    // 0..15
  const int bw0 = n2 * 20 + (kp ^ ((n2 & 3) << 2));
  const int bw1 = (n2 + 1) * 20 + (kp ^ (((n2 + 1) & 3) << 2));
  // B frag read: (n&3) == (lrow&3)
  const int brsel = (lkh ^ (lrow & 3)) * 8;

  f32x4 acc[4][4] = {};
  uint4 pa[4];
  float2 pb0a, pb0b, pb1a, pb1b;

  // ---- prologue ----
  S_LOADB(0, 0) S_LOADB(1, 32)
  S_LOADA(0)
  S_STAGE(0, A0OFF, B0OFF)
  S_LOADA(32)
  S_SYNC()

  for (int s2 = 0; s2 < 8; ++s2) {         // 16 K-steps as even/odd pairs
    const int kt = s2 * 64;
    // even step s=2*s2: compute buf0; prefetch B(s+2); stage (A,B)(s+1)->buf1
    if (s2 < 7) S_LOADB(0, kt + 64)
    S_MFMA(A0OFF, B0OFF)
    S_STAGE(1, A1OFF, B1OFF)
    if (s2 < 7) S_LOADA(kt + 64)
    S_SYNC()
    // odd step: compute buf1; prefetch B(s+2); stage (A,B)(s+1)->buf0
    if (s2 < 7) S_LOADB(1, kt + 96)
    S_MFMA(A1OFF, B1OFF)
    if (s2 < 7) {
      S_STAGE(0, A0OFF, B0OFF)
      S_LOADA(kt + 96)
      S_SYNC()
    }
  }

  // ---- epilogue: scalar stores, 16 lanes x 4B = 64B contiguous per instr ----
  #pragma unroll
  for (int mi = 0; mi < 4; ++mi) {
    #pragma unroll
    for (int r = 0; r < 4; ++r) {
      long gr = mtile + wv * 64 + mi * 16 + lkh * 4 + r;
      float bv = 0.0f;
      if constexpr (BIAS) bv = bias[gr];
      #pragma unroll
      for (int ni = 0; ni < 4; ++ni) {
        long gc = ntile + ni * 16 + lrow;
        float v = acc[mi][ni][r] + bv;
        if constexpr (OUT_BF16)
          ((u16*)Op)[(long)b * o_bstride + gr * ldn + gc] = f2bf(v);
        else
          ((float*)Op)[(long)b * o_bstride + gr * ldn + gc] = v;
      }
    }
  }
}

// ---------------------------------------------------------------------------
// K2: per (b,h): softmax over m of K rows, ctx[d][e] = sum_m Kexp[d][m]*V[e][m]
// ---------------------------------------------------------------------------
__global__ __launch_bounds__(256, 2) void softmax_context(
    const u16* __restrict__ kv, float* __restrict__ ctx)
{
  constexpr int LDE = 132;
  __shared__ float rowmax[64], rowinv[64];
  __shared__ u16 Ke[64 * LDE];
  __shared__ u16 Vs[64 * LDE];
  __shared__ float pr[64 * 68];

  const int bh = blockIdx.x;
  const u16* Kr = kv + (long)(bh >> 3) * (1024 * 1024) + (long)(bh & 7) * (64 * 1024);
  const u16* Vr = Kr + 512 * 1024;

  const int t = threadIdx.x;
  const int lane = t & 63, wv = t >> 6;
  const int lrow = lane & 15, lkh = lane >> 4;
  const int d4 = t >> 2, q4 = t & 3;

  {
    const u16* row = Kr + d4 * 1024 + q4 * 256;
    float mx = -3e38f;
    for (int i = 0; i < 256; i += 8) {
      uint4 v = *(const uint4*)(row + i);
      u32 ws[4] = {v.x, v.y, v.z, v.w};
      #pragma unroll
      for (int j = 0; j < 4; ++j) {
        mx = fmaxf(mx, __builtin_bit_cast(float, ws[j] << 16));
        mx = fmaxf(mx, __builtin_bit_cast(float, ws[j] & 0xffff0000u));
      }
    }
    mx = fmaxf(mx, __shfl_xor(mx, 1));
    mx = fmaxf(mx, __shfl_xor(mx, 2));
    float s = 0.f;
    for (int i = 0; i < 256; i += 8) {
      uint4 v = *(const uint4*)(row + i);
      u32 ws[4] = {v.x, v.y, v.z, v.w};
      #pragma unroll
      for (int j = 0; j < 4; ++j) {
        s += __expf(__builtin_bit_cast(float, ws[j] << 16) - mx);
        s += __expf(__builtin_bit_cast(float, ws[j] & 0xffff0000u) - mx);
      }
    }
    s += __shfl_xor(s, 1);
    s += __shfl_xor(s, 2);
    if (q4 == 0) { rowmax[d4] = mx; rowinv[d4] = 1.f / s; }
  }
  __syncthreads();

  f32x4 cacc[4][4] = {};

  for (int mc = 0; mc < 8; ++mc) {
    {
      int dd = t >> 2, j = t & 3;
      int m0 = mc * 128 + j * 32;
      float mx = rowmax[dd], inv = rowinv[dd];
      const u16* src = Kr + dd * 1024 + m0;
      u16* dst = &Ke[dd * LDE + j * 32];
      #pragma unroll
      for (int cq = 0; cq < 4; ++cq) {
        uint4 v = *(const uint4*)(src + cq * 8);
        u32 in[4] = {v.x, v.y, v.z, v.w};
        u32 out[4];
        #pragma unroll
        for (int j2 = 0; j2 < 4; ++j2) {
          float lo = __builtin_bit_cast(float, in[j2] << 16);
          float hif = __builtin_bit_cast(float, in[j2] & 0xffff0000u);
          out[j2] = (u32)f2bf(__expf(lo - mx) * inv) |
                    ((u32)f2bf(__expf(hif - mx) * inv) << 16);
        }
        *(uint2*)(dst + cq * 8)     = make_uint2(out[0], out[1]);
        *(uint2*)(dst + cq * 8 + 4) = make_uint2(out[2], out[3]);
      }
      const u16* vsrc = Vr + dd * 1024 + m0;
      u16* vdst = &Vs[dd * LDE + j * 32];
      #pragma unroll
      for (int cq = 0; cq < 4; ++cq) {
        uint4 v = *(const uint4*)(vsrc + cq * 8);
        *(uint2*)(vdst + cq * 8)     = make_uint2(v.x, v.y);
        *(uint2*)(vdst + cq * 8 + 4) = make_uint2(v.z, v.w);
      }
    }
    __syncthreads();
    bf16x8 ka[4], vb[4];
    #pragma unroll
    for (int mi = 0; mi < 4; ++mi)
      ka[mi] = ld_frag(&Ke[(mi * 16 + lrow) * LDE + wv * 32 + lkh * 8]);
    #pragma unroll
    for (int ni = 0; ni < 4; ++ni)
      vb[ni] = ld_frag(&Vs[(ni * 16 + lrow) * LDE + wv * 32 + lkh * 8]);
    #pragma unroll
    for (int mi = 0; mi < 4; ++mi)
      #pragma unroll
      for (int ni = 0; ni < 4; ++ni)
        cacc[mi][ni] = __builtin_amdgcn_mfma_f32_16x16x32_bf16(ka[mi], vb[ni], cacc[mi][ni], 0, 0, 0);
    __syncthreads();
  }

  for (int w = 0; w < 4; ++w) {
    if (wv == w) {
      #pragma unroll
      for (int mi = 0; mi < 4; ++mi)
        #pragma unroll
        for (int ni = 0; ni < 4; ++ni)
          #pragma unroll
          for (int r = 0; r < 4; ++r) {
            float* p = &pr[(mi * 16 + lkh * 4 + r) * 68 + (ni * 16 + lrow)];
            float v = cacc[mi][ni][r];
            if (w == 0) *p = v; else *p += v;
          }
    }
    __syncthreads();
  }
  float* cg = ctx + (long)bh * 4096;
  for (int i = 0; i < 16; ++i) {
    int o = t + i * 256;
    cg[o] = 0.125f * pr[(o >> 6) * 68 + (o & 63)];  // fold q-scale
  }
}

// ---------------------------------------------------------------------------
// K3a: U[b][o][h*64+d] = sum_e Wo[o][h*64+e] * ctx[b,h,d,e]
// ---------------------------------------------------------------------------
__global__ __launch_bounds__(256) void compose_u(
    const float* __restrict__ ctx, const float* __restrict__ Wo, u16* __restrict__ U)
{
  __shared__ float cs[16 * 64];
  const int bh = blockIdx.x, dq = blockIdx.y;
  const int b = bh >> 3, h = bh & 7;
  const int t = threadIdx.x;
  const float* cgrp = ctx + (long)bh * 4096 + dq * 16 * 64;
  for (int i = t; i < 1024; i += 256) cs[i] = cgrp[i];
  __syncthreads();
  #pragma unroll
  for (int rep = 0; rep < 2; ++rep) {
    int o = rep * 256 + t;
    const float* wrow = Wo + (long)o * 512 + h * 64;
    float acc[16] = {};
    for (int e = 0; e < 64; ++e) {
      float w = wrow[e];
      #pragma unroll
      for (int dd = 0; dd < 16; ++dd) acc[dd] += w * cs[dd * 64 + e];
    }
    u16* urow = U + (long)b * (512 * 512) + (long)o * 512 + h * 64 + dq * 16;
    #pragma unroll
    for (int dd = 0; dd < 16; ++dd) urow[dd] = f2bf(acc[dd]);
  }
}

// ---------------------------------------------------------------------------
extern "C" void kernel_launch(void* const* d_in, const int* in_sizes, int n_in,
                              void* d_out, int out_size, void* d_ws, size_t ws_size,
                              hipStream_t stream)
{
  const float* x   = (const float*)d_in[0];  // [16, 512, 4096]
  const float* c   = (const float*)d_in[1];  // [16, 512, 1024]
  const float* Wq  = (const float*)d_in[2];  // [512, 512]
  const float* Wkv = (const float*)d_in[3];  // [1024, 512]
  const float* Wo  = (const float*)d_in[4];  // [512, 512]
  const float* bo  = (const float*)d_in[5];  // [512]

  // workspace layout (52.4 MB total)
  char* ws = (char*)d_ws;
  u16*   kv   = (u16*)ws;                      // 16*1024*1024 bf16 = 33.5 MB
  float* ctx  = (float*)(ws + 33554432);       // 16*8*64*64 f32    =  2.1 MB
  u16*   U    = (u16*)(ws + 35651584);         // 16*512*512 bf16   =  8.4 MB
  u16*   Weff = (u16*)(ws + 44040192);         // 16*512*512 bf16   =  8.4 MB
  u16*   Wkvb = (u16*)(ws + 44040192);         // 1 MB, overlaps Weff: consumed by K1
                                               // BEFORE K3b writes Weff

  // K0: Wkv f32 -> bf16
  cvt_f32_bf16<<<dim3(256), 256, 0, stream>>>(Wkv, Wkvb, 65536);
  // K1: kv[b] = Wkv @ c[b]        MT=2, NT=16 -> 512 blocks (2/CU)
  gemm_s<true, false, 2, 16><<<dim3(2 * 16 * 16), 512, 0, stream>>>(
      Wkvb, 0, c, 512L * 1024, kv, 1024L * 1024, nullptr, 1024);
  // K2: softmax + context
  softmax_context<<<dim3(128), 256, 0, stream>>>(kv, ctx);
  // K3a: U = scale * Wo_h @ ctx_h^T
  compose_u<<<dim3(128, 4), 256, 0, stream>>>(ctx, Wo, U);
  // K3b: Weff[b] = U[b] @ Wq      MT=1, NT=8  -> 128 blocks
  gemm_s<true, false, 1, 8><<<dim3(1 * 8 * 16), 512, 0, stream>>>(
      U, 512L * 512, Wq, 0, Weff, 512L * 512, nullptr, 512);
  // K4: Y[b] = Weff[b] @ x[b] + bo   MT=1 (x read once), NT=64 -> 1024 blocks
  gemm_s<false, true, 1, 64><<<dim3(1 * 64 * 16), 512, 0, stream>>>(
      Weff, 512L * 512, x, 512L * 4096, d_out, 512L * 4096, bo, 4096);
}

// Round 12
// 213.139 us; speedup vs baseline: 1.5925x; 1.5925x over previous
//
#include <hip/hip_runtime.h>

// LinearCrossAttention: B=16, N=4096, M=1024, C_in=C_cond=512, HIDDEN=512
#define KDIM 512

typedef __attribute__((ext_vector_type(8))) short bf16x8;
typedef __attribute__((ext_vector_type(4))) float f32x4;
typedef unsigned short u16;
typedef unsigned int u32;

static __device__ __forceinline__ u16 f2bf(float f) {
  u32 u = __builtin_bit_cast(u32, f);
  u32 r = u + 0x7fffu + ((u >> 16) & 1u);   // round-to-nearest-even
  return (u16)(r >> 16);
}
static __device__ __forceinline__ bf16x8 ld_frag(const u16* p) {
  uint2 lo = *(const uint2*)p;
  uint2 hi = *(const uint2*)(p + 4);
  uint4 u = make_uint4(lo.x, lo.y, hi.x, hi.y);
  return __builtin_bit_cast(bf16x8, u);
}

// async global->LDS, 16B per lane; LDS dest is wave-uniform base + lane*16
#define GLOADLDS(g, l) \
  __builtin_amdgcn_global_load_lds( \
      (const __attribute__((address_space(1))) void*)(g), \
      (__attribute__((address_space(3))) void*)(l), 16, 0, 0)

// ---------------------------------------------------------------------------
// prep: f32 -> bf16 (for Wkv), 8 elems/thread
// ---------------------------------------------------------------------------
__global__ __launch_bounds__(256) void cvt_f32_bf16(
    const float* __restrict__ src, u16* __restrict__ dst, int n8)
{
  int i = blockIdx.x * 256 + threadIdx.x;
  if (i >= n8) return;
  float4 a = *(const float4*)(src + (long)i * 8);
  float4 b = *(const float4*)(src + (long)i * 8 + 4);
  u32 w0 = (u32)f2bf(a.x) | ((u32)f2bf(a.y) << 16);
  u32 w1 = (u32)f2bf(a.z) | ((u32)f2bf(a.w) << 16);
  u32 w2 = (u32)f2bf(b.x) | ((u32)f2bf(b.y) << 16);
  u32 w3 = (u32)f2bf(b.z) | ((u32)f2bf(b.w) << 16);
  *(uint4*)(dst + (long)i * 8) = make_uint4(w0, w1, w2, w3);
}

// ---------------------------------------------------------------------------
// gemm_t: R8's frame (BM=512/BN=128/BK=32, 512 thr = 8 waves 4Mx2N, per-wave
// 128x64, LDS double-buffered, depth-2 B reg prefetch, one barrier/K-step,
// __launch_bounds__(512,2) — the only register-clean shape) with ONE change:
//
//   A staged via global_load_lds (async, no VGPR round-trip, no ds_write).
//   LDS A layout: linear [512 rows][64B].  Wave w, issue i writes rows
//   (i*8+w)*16..+15; lane l -> row R0+(l>>2), slot l&3.  SOURCE granule is
//   pre-swizzled: g = (l&3) ^ ((row>>2)&3)  (same 64B line, coalescing
//   intact).  Frag read: slot = lkh ^ ((lrow>>2)&3) -> banks 2-way max
//   (free, m136).
//
// B side verbatim R8 (reg-staged transpose+cvt, pad-36 rows, XOR k-groups).
// LDS 84 KB total; ~170 unified regs -> no spill.
// ---------------------------------------------------------------------------
#define A0OFF 0
#define A1OFF 16384
#define B0OFF 32768
#define B1OFF 37376

#define T_GLOADA(kt, ab) { _Pragma("unroll") \
  for (int i_ = 0; i_ < 4; ++i_) { \
    int r_ = (i_ * 8 + wv) * 16 + (lane >> 2); \
    int g_ = (lane & 3) ^ ((r_ >> 2) & 3); \
    GLOADLDS(Ab + (long)r_ * KDIM + (kt) + g_ * 8, \
             &lds[(ab) + (i_ * 8 + wv) * 512]); } }

#define T_LOADB(set, kt) { \
  pb##set##a = *(const float4*)(Bb + (long)((kt) + krow)     * ldn + nq * 4); \
  pb##set##b = *(const float4*)(Bb + (long)((kt) + krow + 1) * ldn + nq * 4); }

#define T_STAGEB(set, bb) { \
  float f0_[4] = {pb##set##a.x, pb##set##a.y, pb##set##a.z, pb##set##a.w}; \
  float f1_[4] = {pb##set##b.x, pb##set##b.y, pb##set##b.z, pb##set##b.w}; \
  _Pragma("unroll") for (int j_ = 0; j_ < 4; ++j_) { \
    u32 w_ = (u32)f2bf(f0_[j_]) | ((u32)f2bf(f1_[j_]) << 16); \
    *(u32*)&lds[(bb) + (nq * 4 + j_) * 36 + krow] = w_; } }

#define T_MFMA(ab, bb) { \
  bf16x8 bfr_[4]; \
  _Pragma("unroll") for (int ni_ = 0; ni_ < 4; ++ni_) \
    bfr_[ni_] = ld_frag(&lds[(bb) + (wn * 64 + ni_ * 16 + lrow) * 36 + lkh * 8]); \
  __builtin_amdgcn_s_setprio(1); \
  _Pragma("unroll") for (int mi_ = 0; mi_ < 8; ++mi_) { \
    int r_ = wm * 128 + mi_ * 16 + lrow; \
    bf16x8 af_ = *(const bf16x8*)&lds[(ab) + r_ * 32 + arsel]; \
    _Pragma("unroll") for (int ni_ = 0; ni_ < 4; ++ni_) \
      acc[mi_][ni_] = __builtin_amdgcn_mfma_f32_16x16x32_bf16(af_, bfr_[ni_], acc[mi_][ni_], 0, 0, 0); } \
  __builtin_amdgcn_s_setprio(0); }

template<bool OUT_BF16, bool BIAS, int MT, int NT>
__global__ __launch_bounds__(512, 2) void gemm_t(
    const u16* __restrict__ Ap, long a_bstride,
    const float* __restrict__ Bp, long b_bstride,
    void* __restrict__ Op, long o_bstride,
    const float* __restrict__ bias, int ldn)
{
  __shared__ u16 lds[41984];               // 84 KB: A 2x32KB linear, B 2x9.2KB

  const int d = blockIdx.x;                // mt innermost: B-slice sharers adjacent
  const int mt = d % MT;
  const int nt = (d / MT) % NT;
  const int b  = d / (MT * NT);
  const long mtile = (long)mt * 512;
  const long ntile = (long)nt * 128;
  const u16* Ab = Ap + (long)b * a_bstride + mtile * KDIM;
  const float* Bb = Bp + (long)b * b_bstride + ntile;

  const int t = threadIdx.x;
  const int lane = t & 63, wv = t >> 6;
  const int wm = wv >> 1, wn = wv & 1;     // 4 x 2 wave grid
  const int lrow = lane & 15, lkh = lane >> 4;
  const int arsel = (lkh ^ ((lrow >> 2) & 3)) * 8;   // A frag read slot (u16)

  // B staging map (verbatim R8)
  const int nq = t & 31;                   // 4-col group (128 cols)
  const int hi = (t >> 8) & 1;
  const int kq = ((t >> 5) & 7) ^ ((t >> 2) & 7);    // XOR-spread k-group
  const int krow = kq * 4 + hi * 2;        // adjacent k-row pair

  f32x4 acc[8][4] = {};
  float4 pb0a, pb0b, pb1a, pb1b;

  // ---- prologue: B(0) regs + A(0) async, stage B(0), fence ----
  T_LOADB(0, 0)
  T_GLOADA(0, A0OFF)
  T_STAGEB(0, B0OFF)
  __syncthreads();                          // drains gload A(0) too

  for (int s2 = 0; s2 < 8; ++s2) {          // 16 K-steps as even/odd pairs
    const int kt = s2 * 64;
    // even step: prefetch (s+1) -> bufs1; compute bufs0
    T_LOADB(1, kt + 32)
    T_GLOADA(kt + 32, A1OFF)
    T_MFMA(A0OFF, B0OFF)
    T_STAGEB(1, B1OFF)
    __syncthreads();
    // odd step: prefetch (s+1) -> bufs0; compute bufs1
    if (s2 < 7) {
      T_LOADB(0, kt + 64)
      T_GLOADA(kt + 64, A0OFF)
    }
    T_MFMA(A1OFF, B1OFF)
    if (s2 < 7) {
      T_STAGEB(0, B0OFF)
      __syncthreads();
    }
  }

  // ---- epilogue: scalar stores, 16 lanes x 4B = 64B contiguous per instr ----
  #pragma unroll
  for (int mi = 0; mi < 8; ++mi) {
    #pragma unroll
    for (int r = 0; r < 4; ++r) {
      long gr = mtile + wm * 128 + mi * 16 + lkh * 4 + r;
      float bv = 0.0f;
      if constexpr (BIAS) bv = bias[gr];
      #pragma unroll
      for (int ni = 0; ni < 4; ++ni) {
        long gc = ntile + wn * 64 + ni * 16 + lrow;
        float v = acc[mi][ni][r] + bv;
        if constexpr (OUT_BF16)
          ((u16*)Op)[(long)b * o_bstride + gr * ldn + gc] = f2bf(v);
        else
          ((float*)Op)[(long)b * o_bstride + gr * ldn + gc] = v;
      }
    }
  }
}

// ---------------------------------------------------------------------------
// K2: per (b,h): softmax over m of K rows, ctx[d][e] = sum_m Kexp[d][m]*V[e][m]
// ---------------------------------------------------------------------------
__global__ __launch_bounds__(256, 2) void softmax_context(
    const u16* __restrict__ kv, float* __restrict__ ctx)
{
  constexpr int LDE = 132;
  __shared__ float rowmax[64], rowinv[64];
  __shared__ u16 Ke[64 * LDE];
  __shared__ u16 Vs[64 * LDE];
  __shared__ float pr[64 * 68];

  const int bh = blockIdx.x;
  const u16* Kr = kv + (long)(bh >> 3) * (1024 * 1024) + (long)(bh & 7) * (64 * 1024);
  const u16* Vr = Kr + 512 * 1024;

  const int t = threadIdx.x;
  const int lane = t & 63, wv = t >> 6;
  const int lrow = lane & 15, lkh = lane >> 4;
  const int d4 = t >> 2, q4 = t & 3;

  {
    const u16* row = Kr + d4 * 1024 + q4 * 256;
    float mx = -3e38f;
    for (int i = 0; i < 256; i += 8) {
      uint4 v = *(const uint4*)(row + i);
      u32 ws[4] = {v.x, v.y, v.z, v.w};
      #pragma unroll
      for (int j = 0; j < 4; ++j) {
        mx = fmaxf(mx, __builtin_bit_cast(float, ws[j] << 16));
        mx = fmaxf(mx, __builtin_bit_cast(float, ws[j] & 0xffff0000u));
      }
    }
    mx = fmaxf(mx, __shfl_xor(mx, 1));
    mx = fmaxf(mx, __shfl_xor(mx, 2));
    float s = 0.f;
    for (int i = 0; i < 256; i += 8) {
      uint4 v = *(const uint4*)(row + i);
      u32 ws[4] = {v.x, v.y, v.z, v.w};
      #pragma unroll
      for (int j = 0; j < 4; ++j) {
        s += __expf(__builtin_bit_cast(float, ws[j] << 16) - mx);
        s += __expf(__builtin_bit_cast(float, ws[j] & 0xffff0000u) - mx);
      }
    }
    s += __shfl_xor(s, 1);
    s += __shfl_xor(s, 2);
    if (q4 == 0) { rowmax[d4] = mx; rowinv[d4] = 1.f / s; }
  }
  __syncthreads();

  f32x4 cacc[4][4] = {};

  for (int mc = 0; mc < 8; ++mc) {
    {
      int dd = t >> 2, j = t & 3;
      int m0 = mc * 128 + j * 32;
      float mx = rowmax[dd], inv = rowinv[dd];
      const u16* src = Kr + dd * 1024 + m0;
      u16* dst = &Ke[dd * LDE + j * 32];
      #pragma unroll
      for (int cq = 0; cq < 4; ++cq) {
        uint4 v = *(const uint4*)(src + cq * 8);
        u32 in[4] = {v.x, v.y, v.z, v.w};
        u32 out[4];
        #pragma unroll
        for (int j2 = 0; j2 < 4; ++j2) {
          float lo = __builtin_bit_cast(float, in[j2] << 16);
          float hif = __builtin_bit_cast(float, in[j2] & 0xffff0000u);
          out[j2] = (u32)f2bf(__expf(lo - mx) * inv) |
                    ((u32)f2bf(__expf(hif - mx) * inv) << 16);
        }
        *(uint2*)(dst + cq * 8)     = make_uint2(out[0], out[1]);
        *(uint2*)(dst + cq * 8 + 4) = make_uint2(out[2], out[3]);
      }
      const u16* vsrc = Vr + dd * 1024 + m0;
      u16* vdst = &Vs[dd * LDE + j * 32];
      #pragma unroll
      for (int cq = 0; cq < 4; ++cq) {
        uint4 v = *(const uint4*)(vsrc + cq * 8);
        *(uint2*)(vdst + cq * 8)     = make_uint2(v.x, v.y);
        *(uint2*)(vdst + cq * 8 + 4) = make_uint2(v.z, v.w);
      }
    }
    __syncthreads();
    bf16x8 ka[4], vb[4];
    #pragma unroll
    for (int mi = 0; mi < 4; ++mi)
      ka[mi] = ld_frag(&Ke[(mi * 16 + lrow) * LDE + wv * 32 + lkh * 8]);
    #pragma unroll
    for (int ni = 0; ni < 4; ++ni)
      vb[ni] = ld_frag(&Vs[(ni * 16 + lrow) * LDE + wv * 32 + lkh * 8]);
    #pragma unroll
    for (int mi = 0; mi < 4; ++mi)
      #pragma unroll
      for (int ni = 0; ni < 4; ++ni)
        cacc[mi][ni] = __builtin_amdgcn_mfma_f32_16x16x32_bf16(ka[mi], vb[ni], cacc[mi][ni], 0, 0, 0);
    __syncthreads();
  }

  for (int w = 0; w < 4; ++w) {
    if (wv == w) {
      #pragma unroll
      for (int mi = 0; mi < 4; ++mi)
        #pragma unroll
        for (int ni = 0; ni < 4; ++ni)
          #pragma unroll
          for (int r = 0; r < 4; ++r) {
            float* p = &pr[(mi * 16 + lkh * 4 + r) * 68 + (ni * 16 + lrow)];
            float v = cacc[mi][ni][r];
            if (w == 0) *p = v; else *p += v;
          }
    }
    __syncthreads();
  }
  float* cg = ctx + (long)bh * 4096;
  for (int i = 0; i < 16; ++i) {
    int o = t + i * 256;
    cg[o] = 0.125f * pr[(o >> 6) * 68 + (o & 63)];  // fold q-scale
  }
}

// ---------------------------------------------------------------------------
// K3a: U[b][o][h*64+d] = sum_e Wo[o][h*64+e] * ctx[b,h,d,e]
// ---------------------------------------------------------------------------
__global__ __launch_bounds__(256) void compose_u(
    const float* __restrict__ ctx, const float* __restrict__ Wo, u16* __restrict__ U)
{
  __shared__ float cs[16 * 64];
  const int bh = blockIdx.x, dq = blockIdx.y;
  const int b = bh >> 3, h = bh & 7;
  const int t = threadIdx.x;
  const float* cgrp = ctx + (long)bh * 4096 + dq * 16 * 64;
  for (int i = t; i < 1024; i += 256) cs[i] = cgrp[i];
  __syncthreads();
  #pragma unroll
  for (int rep = 0; rep < 2; ++rep) {
    int o = rep * 256 + t;
    const float* wrow = Wo + (long)o * 512 + h * 64;
    float acc[16] = {};
    for (int e = 0; e < 64; ++e) {
      float w = wrow[e];
      #pragma unroll
      for (int dd = 0; dd < 16; ++dd) acc[dd] += w * cs[dd * 64 + e];
    }
    u16* urow = U + (long)b * (512 * 512) + (long)o * 512 + h * 64 + dq * 16;
    #pragma unroll
    for (int dd = 0; dd < 16; ++dd) urow[dd] = f2bf(acc[dd]);
  }
}

// ---------------------------------------------------------------------------
extern "C" void kernel_launch(void* const* d_in, const int* in_sizes, int n_in,
                              void* d_out, int out_size, void* d_ws, size_t ws_size,
                              hipStream_t stream)
{
  const float* x   = (const float*)d_in[0];  // [16, 512, 4096]
  const float* c   = (const float*)d_in[1];  // [16, 512, 1024]
  const float* Wq  = (const float*)d_in[2];  // [512, 512]
  const float* Wkv = (const float*)d_in[3];  // [1024, 512]
  const float* Wo  = (const float*)d_in[4];  // [512, 512]
  const float* bo  = (const float*)d_in[5];  // [512]

  // workspace layout (52.4 MB total)
  char* ws = (char*)d_ws;
  u16*   kv   = (u16*)ws;                      // 16*1024*1024 bf16 = 33.5 MB
  float* ctx  = (float*)(ws + 33554432);       // 16*8*64*64 f32    =  2.1 MB
  u16*   U    = (u16*)(ws + 35651584);         // 16*512*512 bf16   =  8.4 MB
  u16*   Weff = (u16*)(ws + 44040192);         // 16*512*512 bf16   =  8.4 MB
  u16*   Wkvb = (u16*)(ws + 44040192);         // 1 MB, overlaps Weff: consumed by K1
                                               // BEFORE K3b writes Weff

  // K0: Wkv f32 -> bf16
  cvt_f32_bf16<<<dim3(256), 256, 0, stream>>>(Wkv, Wkvb, 65536);
  // K1: kv[b] = Wkv @ c[b]        MT=2, NT=8  -> 256 blocks
  gemm_t<true, false, 2, 8><<<dim3(2 * 8 * 16), 512, 0, stream>>>(
      Wkvb, 0, c, 512L * 1024, kv, 1024L * 1024, nullptr, 1024);
  // K2: softmax + context
  softmax_context<<<dim3(128), 256, 0, stream>>>(kv, ctx);
  // K3a: U = scale * Wo_h @ ctx_h^T
  compose_u<<<dim3(128, 4), 256, 0, stream>>>(ctx, Wo, U);
  // K3b: Weff[b] = U[b] @ Wq      MT=1, NT=4  -> 64 blocks
  gemm_t<true, false, 1, 4><<<dim3(1 * 4 * 16), 512, 0, stream>>>(
      U, 512L * 512, Wq, 0, Weff, 512L * 512, nullptr, 512);
  // K4: Y[b] = Weff[b] @ x[b] + bo   MT=1 (x read once), NT=32 -> 512 blocks
  gemm_t<false, true, 1, 32><<<dim3(1 * 32 * 16), 512, 0, stream>>>(
      Weff, 512L * 512, x, 512L * 4096, d_out, 512L * 4096, bo, 4096);
}